// Round 10
// baseline (270.115 us; speedup 1.0000x reference)
//
#include <hip/hip_runtime.h>
#include <hip/hip_bf16.h>
#include <hip/hip_fp16.h>

// ---------------------------------------------------------------------------
// GCN link prediction (math fp32, fp16 tables, MFMA GEMMs):
//   prep+count -> deg/partials -> scan(2-level) -> CSR fill(no atomic) ->
//   mfma gemm1 -> agg128 relu -> mfma gemm2 -> agg64 -> decode
// Round 10 = round-9 passing code + ONE concept: half-wave edge pairing in
// agg64/agg128/decode using ONLY uniform-index shfl + lane<32 select
// (no varying-index shfl, no divergent shuffle tails — zero-weight padding).
// Plus trivial prep+count fusion (one launch saved).
// ---------------------------------------------------------------------------

typedef _Float16 half8 __attribute__((ext_vector_type(8)));
typedef _Float16 half4v __attribute__((ext_vector_type(4)));
typedef float   floatx4 __attribute__((ext_vector_type(4)));

// Fused: x->fp16, W1/W2 -> fp16 transposed, edge count(+rank).
__global__ __launch_bounds__(256)
void prep_count_kernel(const float* __restrict__ x, const float* __restrict__ W1,
                       const float* __restrict__ W2, _Float16* __restrict__ Xh,
                       _Float16* __restrict__ W1t, _Float16* __restrict__ W2t,
                       const int* __restrict__ col, int* __restrict__ cnt,
                       int* __restrict__ eoff, int n4, int ne) {
  int i = blockIdx.x * 256 + threadIdx.x;
  if (i < n4) {
    float4 v = ((const float4*)x)[i];
    half4v h; h[0] = (_Float16)v.x; h[1] = (_Float16)v.y;
    h[2] = (_Float16)v.z; h[3] = (_Float16)v.w;
    ((half4v*)Xh)[i] = h;
  }
  if (i < 128 * 128) {  // W1t[n*128+k] = W1[k*128+n]
    int k = i >> 7, n = i & 127;
    W1t[(size_t)n * 128 + k] = (_Float16)W1[i];
  }
  if (i < 128 * 64) {   // W2t[n*128+k] = W2[k*64+n]
    int k = i >> 6, n = i & 63;
    W2t[(size_t)n * 128 + k] = (_Float16)W2[i];
  }
  if (i < ne) eoff[i] = atomicAdd(&cnt[col[i]], 1);
}

__global__ __launch_bounds__(256)
void partial_deg_kernel(const int* __restrict__ cnt, int* __restrict__ part,
                        float* __restrict__ dis, float* __restrict__ dinv, int n) {
  int i = blockIdx.x * 256 + threadIdx.x;
  int c = (i < n) ? cnt[i] : 0;
  if (i < n) {
    float d = (float)(c + 1);   // +1 self loop
    dinv[i] = 1.0f / d;
    dis[i]  = rsqrtf(d);
  }
  int lane = threadIdx.x & 63, w = threadIdx.x >> 6;
  int s = c;
#pragma unroll
  for (int m = 32; m >= 1; m >>= 1) s += __shfl_xor(s, m, 64);
  __shared__ int wp[4];
  if (lane == 0) wp[w] = s;
  __syncthreads();
  if (threadIdx.x == 0) part[blockIdx.x] = wp[0] + wp[1] + wp[2] + wp[3];
}

__device__ inline int wave_incl_scan(int v, int lane) {
#pragma unroll
  for (int off = 1; off < 64; off <<= 1) {
    int u = __shfl_up(v, off, 64);
    if (lane >= off) v += u;
  }
  return v;
}

__global__ __launch_bounds__(256)
void scan_part_kernel(int* __restrict__ part, int nb) {
  int t = threadIdx.x;
  int v = (t < nb) ? part[t] : 0;
  int lane = t & 63, w = t >> 6;
  int inc = wave_incl_scan(v, lane);
  __shared__ int wp[4];
  if (lane == 63) wp[w] = inc;
  __syncthreads();
  if (t == 0) { int s = 0; for (int k = 0; k < 4; ++k) { int x = wp[k]; wp[k] = s; s += x; } }
  __syncthreads();
  int excl = wp[w] + inc - v;
  if (t < nb) part[t] = excl;
}

__global__ __launch_bounds__(256)
void scan_final_kernel(const int* __restrict__ cnt, const int* __restrict__ part,
                       int* __restrict__ row_ptr, int n) {
  int t = threadIdx.x;
  int i = blockIdx.x * 256 + t;
  int v = (i < n) ? cnt[i] : 0;
  int lane = t & 63, w = t >> 6;
  int inc = wave_incl_scan(v, lane);
  __shared__ int wp[4];
  if (lane == 63) wp[w] = inc;
  __syncthreads();
  if (t == 0) { int s = 0; for (int k = 0; k < 4; ++k) { int x = wp[k]; wp[k] = s; s += x; } }
  __syncthreads();
  int excl = part[blockIdx.x] + wp[w] + inc - v;
  if (i < n) {
    row_ptr[i] = excl;
    if (i == n - 1) row_ptr[n] = excl + v;
  }
}

__global__ __launch_bounds__(256)
void fill_kernel(const int* __restrict__ row, const int* __restrict__ col,
                 const int* __restrict__ eoff, const float* __restrict__ dis,
                 const int* __restrict__ row_ptr, int2* __restrict__ ep, int ne) {
  int e = blockIdx.x * 256 + threadIdx.x;
  if (e >= ne) return;
  int r = row[e], c = col[e];
  int pos = row_ptr[c] + eoff[e];
  float nrm = dis[r] * dis[c];
  ep[pos] = make_int2(r, __float_as_int(nrm));
}

// Y[N,M] = Xh[N,128] @ Wt^T (Wt is [M][128], fp16). MFMA 16x16x32, fragments
// straight from global; D map col=lane&15,row=quad*4+r (HW-verified).
template<int M>
__global__ __launch_bounds__(256)
void gemm_mfma_kernel(const _Float16* __restrict__ Xh,
                      const _Float16* __restrict__ Wt,
                      _Float16* __restrict__ Y, int N) {
  constexpr int K = 128;
  constexpr int CT = M / 16;
  const int t = threadIdx.x;
  const int lane = t & 63;
  const int i16 = lane & 15;
  const int quad = lane >> 4;
  const int row0 = blockIdx.x * 64 + (t >> 6) * 16;
  int arow = row0 + i16;
  if (arow >= N) arow = N - 1;
  const _Float16* aptr = Xh + (size_t)arow * K + quad * 8;
  floatx4 acc[CT];
#pragma unroll
  for (int c = 0; c < CT; ++c) acc[c] = (floatx4){0.f, 0.f, 0.f, 0.f};
#pragma unroll
  for (int k0 = 0; k0 < K; k0 += 32) {
    half8 a = *(const half8*)(aptr + k0);
#pragma unroll
    for (int c = 0; c < CT; ++c) {
      half8 b = *(const half8*)(Wt + (size_t)(c * 16 + i16) * K + quad * 8 + k0);
      acc[c] = __builtin_amdgcn_mfma_f32_16x16x32_f16(a, b, acc[c], 0, 0, 0);
    }
  }
#pragma unroll
  for (int c = 0; c < CT; ++c) {
#pragma unroll
    for (int r = 0; r < 4; ++r) {
      int gr = row0 + quad * 4 + r;
      if (gr < N) Y[(size_t)gr * M + c * 16 + i16] = (_Float16)acc[c][r];
    }
  }
}

// CH=128 aggregation. Half-wave edge pairing: uniform shfl broadcasts of edge
// (k, k+1); lane<32 selects edge k, upper half edge k+1 (zero weight pad for
// odd tails). Each lane loads 8B = 4 fp16 channels at [sub]; one instruction
// covers two 256B source rows. Halves combined via shfl_xor 32.
template<bool RELU>
__global__ __launch_bounds__(256)
void agg128h_kernel(const __half* __restrict__ xw, const int* __restrict__ row_ptr,
                    const int2* __restrict__ ep, const float* __restrict__ deg_inv,
                    const float* __restrict__ bias, __half* __restrict__ out, int n) {
  int wave = (blockIdx.x * 256 + threadIdx.x) >> 6;
  int lane = threadIdx.x & 63;
  if (wave >= n) return;
  const int node = wave;
  const int s0 = row_ptr[node], s1 = row_ptr[node + 1];
  const int sub = lane & 31;
  const bool lower = (lane < 32);
  floatx4 acc0 = {0.f, 0.f, 0.f, 0.f}, acc1 = {0.f, 0.f, 0.f, 0.f};
  for (int base = s0; base < s1; base += 64) {
    int m = s1 - base; if (m > 64) m = 64;   // wave-uniform
    int2 ed = make_int2(0, 0);
    if (lane < m) ed = ep[base + lane];
    for (int k = 0; k < m; k += 4) {
      // pair A: edges k, k+1
      {
        int   sa = __shfl(ed.x, k, 64);
        float wa = __int_as_float(__shfl(ed.y, k, 64));
        int sb = sa; float wb = 0.f;
        if (k + 1 < m) {
          sb = __shfl(ed.x, k + 1, 64);
          wb = __int_as_float(__shfl(ed.y, k + 1, 64));
        }
        int   s = lower ? sa : sb;
        float w = lower ? wa : wb;
        float2 raw = ((const float2*)(xw + (size_t)s * 128))[sub];
        const __half2* hp = (const __half2*)&raw;
        float2 lo = __half22float2(hp[0]);
        float2 hi = __half22float2(hp[1]);
        acc0[0] = fmaf(w, lo.x, acc0[0]); acc0[1] = fmaf(w, lo.y, acc0[1]);
        acc0[2] = fmaf(w, hi.x, acc0[2]); acc0[3] = fmaf(w, hi.y, acc0[3]);
      }
      // pair B: edges k+2, k+3
      if (k + 2 < m) {
        int   sa = __shfl(ed.x, k + 2, 64);
        float wa = __int_as_float(__shfl(ed.y, k + 2, 64));
        int sb = sa; float wb = 0.f;
        if (k + 3 < m) {
          sb = __shfl(ed.x, k + 3, 64);
          wb = __int_as_float(__shfl(ed.y, k + 3, 64));
        }
        int   s = lower ? sa : sb;
        float w = lower ? wa : wb;
        float2 raw = ((const float2*)(xw + (size_t)s * 128))[sub];
        const __half2* hp = (const __half2*)&raw;
        float2 lo = __half22float2(hp[0]);
        float2 hi = __half22float2(hp[1]);
        acc1[0] = fmaf(w, lo.x, acc1[0]); acc1[1] = fmaf(w, lo.y, acc1[1]);
        acc1[2] = fmaf(w, hi.x, acc1[2]); acc1[3] = fmaf(w, hi.y, acc1[3]);
      }
    }
  }
#pragma unroll
  for (int j = 0; j < 4; ++j) {
    acc0[j] += acc1[j];
    acc0[j] += __shfl_xor(acc0[j], 32, 64);
  }
  if (lower) {
    float di = deg_inv[node];
    float2 sraw = ((const float2*)(xw + (size_t)node * 128))[sub];
    const __half2* sp = (const __half2*)&sraw;
    float2 slo = __half22float2(sp[0]);
    float2 shi = __half22float2(sp[1]);
    float4 bv = ((const float4*)bias)[sub];
    float o0 = acc0[0] + slo.x * di + bv.x;
    float o1 = acc0[1] + slo.y * di + bv.y;
    float o2 = acc0[2] + shi.x * di + bv.z;
    float o3 = acc0[3] + shi.y * di + bv.w;
    if (RELU) {
      o0 = fmaxf(o0, 0.f); o1 = fmaxf(o1, 0.f);
      o2 = fmaxf(o2, 0.f); o3 = fmaxf(o3, 0.f);
    }
    __half2 h2[2];
    h2[0] = __float22half2_rn(make_float2(o0, o1));
    h2[1] = __float22half2_rn(make_float2(o2, o3));
    *(float2*)(out + (size_t)node * 128 + 4 * sub) = *(const float2*)h2;
  }
}

// CH=64 aggregation, same pairing; lane loads half2 (2 ch) at [sub].
template<bool RELU>
__global__ __launch_bounds__(256)
void agg64h_kernel(const __half* __restrict__ xw, const int* __restrict__ row_ptr,
                   const int2* __restrict__ ep, const float* __restrict__ deg_inv,
                   const float* __restrict__ bias, __half* __restrict__ out, int n) {
  int wave = (blockIdx.x * 256 + threadIdx.x) >> 6;
  int lane = threadIdx.x & 63;
  if (wave >= n) return;
  const int node = wave;
  const int s0 = row_ptr[node], s1 = row_ptr[node + 1];
  const int sub = lane & 31;
  const bool lower = (lane < 32);
  float2 acc0 = make_float2(0.f, 0.f), acc1 = make_float2(0.f, 0.f);
  for (int base = s0; base < s1; base += 64) {
    int m = s1 - base; if (m > 64) m = 64;
    int2 ed = make_int2(0, 0);
    if (lane < m) ed = ep[base + lane];
    for (int k = 0; k < m; k += 4) {
      {
        int   sa = __shfl(ed.x, k, 64);
        float wa = __int_as_float(__shfl(ed.y, k, 64));
        int sb = sa; float wb = 0.f;
        if (k + 1 < m) {
          sb = __shfl(ed.x, k + 1, 64);
          wb = __int_as_float(__shfl(ed.y, k + 1, 64));
        }
        int   s = lower ? sa : sb;
        float w = lower ? wa : wb;
        float2 v = __half22float2(((const __half2*)(xw + (size_t)s * 64))[sub]);
        acc0.x = fmaf(w, v.x, acc0.x); acc0.y = fmaf(w, v.y, acc0.y);
      }
      if (k + 2 < m) {
        int   sa = __shfl(ed.x, k + 2, 64);
        float wa = __int_as_float(__shfl(ed.y, k + 2, 64));
        int sb = sa; float wb = 0.f;
        if (k + 3 < m) {
          sb = __shfl(ed.x, k + 3, 64);
          wb = __int_as_float(__shfl(ed.y, k + 3, 64));
        }
        int   s = lower ? sa : sb;
        float w = lower ? wa : wb;
        float2 v = __half22float2(((const __half2*)(xw + (size_t)s * 64))[sub]);
        acc1.x = fmaf(w, v.x, acc1.x); acc1.y = fmaf(w, v.y, acc1.y);
      }
    }
  }
  acc0.x += acc1.x; acc0.y += acc1.y;
  acc0.x += __shfl_xor(acc0.x, 32, 64);
  acc0.y += __shfl_xor(acc0.y, 32, 64);
  if (lower) {
    float di = deg_inv[node];
    float2 sv = __half22float2(((const __half2*)(xw + (size_t)node * 64))[sub]);
    float2 bv = ((const float2*)bias)[sub];
    float ox = acc0.x + sv.x * di + bv.x;
    float oy = acc0.y + sv.y * di + bv.y;
    if (RELU) { ox = fmaxf(ox, 0.f); oy = fmaxf(oy, 0.f); }
    ((__half2*)(out + (size_t)node * 64))[sub] = __float22half2_rn(make_float2(ox, oy));
  }
}

// Decode: one wave per label edge; lower half loads z[src], upper half z[dst]
// (half2 each). Product symmetric after shfl_xor 32; 32-lane reduce per half.
__global__ __launch_bounds__(256)
void decode_kernel(const __half* __restrict__ z, const int* __restrict__ eli,
                   float* __restrict__ out, int nl) {
  int wave = (blockIdx.x * 256 + threadIdx.x) >> 6;
  int lane = threadIdx.x & 63;
  if (wave >= nl) return;
  int src = eli[wave];
  int dst = eli[nl + wave];
  int node = (lane < 32) ? src : dst;
  int sub = lane & 31;
  float2 v = __half22float2(((const __half2*)(z + (size_t)node * 64))[sub]);
  float ox = __shfl_xor(v.x, 32, 64);
  float oy = __shfl_xor(v.y, 32, 64);
  float p = v.x * ox + v.y * oy;   // identical in both halves
#pragma unroll
  for (int m = 16; m >= 1; m >>= 1) p += __shfl_xor(p, m, 64);
  if (lane == 0) out[wave] = p;
}

extern "C" void kernel_launch(void* const* d_in, const int* in_sizes, int n_in,
                              void* d_out, int out_size, void* d_ws, size_t ws_size,
                              hipStream_t stream) {
  const float* x  = (const float*)d_in[0];
  const float* W1 = (const float*)d_in[1];
  const float* b1 = (const float*)d_in[2];
  const float* W2 = (const float*)d_in[3];
  const float* b2 = (const float*)d_in[4];
  const int* eidx = (const int*)d_in[5];
  const int* eli  = (const int*)d_in[6];
  const int N  = in_sizes[0] / 128;
  const int E  = in_sizes[5] / 2;
  const int NL = in_sizes[6] / 2;
  float* out = (float*)d_out;

  char* ws = (char*)d_ws;
  size_t off = 0;
  auto alloc = [&](size_t bytes) -> char* {
    char* p = ws + off;
    off = (off + bytes + 255) & ~(size_t)255;
    return p;
  };
  const int NB = (N + 255) / 256;
  float*    dis   = (float*)   alloc((size_t)N * 4);
  float*    dinv  = (float*)   alloc((size_t)N * 4);
  int*      cnt   = (int*)     alloc((size_t)N * 4);
  int*      rowp  = (int*)     alloc((size_t)(N + 1) * 4);
  int*      part  = (int*)     alloc((size_t)NB * 4);
  int*      eoff  = (int*)     alloc((size_t)E * 4);
  int2*     ep    = (int2*)    alloc((size_t)E * 8);
  _Float16* Xh    = (_Float16*)alloc((size_t)N * 128 * 2);
  _Float16* W1t   = (_Float16*)alloc((size_t)128 * 128 * 2);
  _Float16* W2t   = (_Float16*)alloc((size_t)64 * 128 * 2);
  __half*   bufA  = (__half*)  alloc((size_t)N * 128 * 2);
  __half*   bufB  = (__half*)  alloc((size_t)N * 128 * 2);
  __half*   bufC  = (__half*)  alloc((size_t)N * 64 * 2);
  __half*   z     = (__half*)  alloc((size_t)N * 64 * 2);
  (void)ws_size; (void)n_in; (void)out_size;

  const int* row = eidx;      // edge_index[0]
  const int* col = eidx + E;  // edge_index[1]

  hipMemsetAsync(cnt, 0, (size_t)N * 4, stream);
  const int n4 = N * 32;  // N*128/4 float4 groups (> E)
  prep_count_kernel<<<(n4 + 255) / 256, 256, 0, stream>>>(
      x, W1, W2, Xh, W1t, W2t, col, cnt, eoff, n4, E);
  partial_deg_kernel<<<NB, 256, 0, stream>>>(cnt, part, dis, dinv, N);
  scan_part_kernel<<<1, 256, 0, stream>>>(part, NB);
  scan_final_kernel<<<NB, 256, 0, stream>>>(cnt, part, rowp, N);
  fill_kernel<<<(E + 255) / 256, 256, 0, stream>>>(row, col, eoff, dis, rowp, ep, E);
  // conv1: bufA = half(Xh@W1); bufB = half(relu(agg(bufA)+dinv*bufA+b1))
  gemm_mfma_kernel<128><<<(N + 63) / 64, 256, 0, stream>>>(Xh, W1t, (_Float16*)bufA, N);
  agg128h_kernel<true><<<(N + 3) / 4, 256, 0, stream>>>(bufA, rowp, ep, dinv, b1, bufB, N);
  // conv2: bufC = half(bufB@W2); z = half(agg(bufC)+dinv*bufC+b2)
  gemm_mfma_kernel<64><<<(N + 63) / 64, 256, 0, stream>>>((const _Float16*)bufB, W2t,
                                                          (_Float16*)bufC, N);
  agg64h_kernel<false><<<(N + 3) / 4, 256, 0, stream>>>(bufC, rowp, ep, dinv, b2, z, N);
  // decode
  decode_kernel<<<(NL + 3) / 4, 256, 0, stream>>>(z, eli, out, NL);
}